// Round 1
// baseline (3941.098 us; speedup 1.0000x reference)
//
#include <hip/hip_runtime.h>
#include <hip/hip_bf16.h>
#include <math.h>

// Problem constants
#define BB    16
#define LS    256
#define LT    128
#define EMB   128
#define HID   256
#define G4    1024      // 4*HID
#define VOCAB 32000

// LSTM slicing: 16 slice-WGs per batch, each owns 16 hidden units (64 gate cols)
#define NSLICE 16
#define UPS    16       // units per slice
#define CPS    64       // gate columns per slice

// ---------------------------------------------------------------------------
// Kernel 1: xz = emb[idx] @ Wk + b   (input projection, precomputed per t)
// grid = rows/8, block = 256. Each block: 8 rows, each thread 4 cols x 8 rows.
// ---------------------------------------------------------------------------
__global__ __launch_bounds__(256) void embed_proj_kernel(
    const int* __restrict__ idx, const float* __restrict__ emb,
    const float* __restrict__ Wk, const float* __restrict__ bias,
    float* __restrict__ xz)
{
  __shared__ float e[8][EMB];
  const int row0 = blockIdx.x * 8;
  const int tid = threadIdx.x;

  for (int i = tid; i < 8 * EMB; i += 256) {
    int r = i >> 7, k = i & 127;
    int token = idx[row0 + r];
    e[r][k] = emb[(size_t)token * EMB + k];
  }
  __syncthreads();

  float acc[4][8];
#pragma unroll
  for (int q = 0; q < 4; ++q)
#pragma unroll
    for (int r = 0; r < 8; ++r) acc[q][r] = 0.0f;

  for (int k = 0; k < EMB; ++k) {
    float w0 = Wk[(size_t)k * G4 + 0 * 256 + tid];
    float w1 = Wk[(size_t)k * G4 + 1 * 256 + tid];
    float w2 = Wk[(size_t)k * G4 + 2 * 256 + tid];
    float w3 = Wk[(size_t)k * G4 + 3 * 256 + tid];
#pragma unroll
    for (int r = 0; r < 8; ++r) {
      float ev = e[r][k];
      acc[0][r] = fmaf(ev, w0, acc[0][r]);
      acc[1][r] = fmaf(ev, w1, acc[1][r]);
      acc[2][r] = fmaf(ev, w2, acc[2][r]);
      acc[3][r] = fmaf(ev, w3, acc[3][r]);
    }
  }
#pragma unroll
  for (int q = 0; q < 4; ++q) {
    float bb = bias[q * 256 + tid];
#pragma unroll
    for (int r = 0; r < 8; ++r)
      xz[(size_t)(row0 + r) * G4 + q * 256 + tid] = acc[q][r] + bb;
  }
}

// ---------------------------------------------------------------------------
// Kernel 2: LSTM recurrence.
// blockIdx.x = s*16 + b  (slice-major so all 16 slices of batch b share an XCD
// under round-robin %8 dispatch). Each WG holds Wr[:, its 64 cols] in LDS.
// Cross-WG per-step sync: agent-scope h stores + counter flag + spin.
// Grid = 256 blocks (<= 256 CUs -> all co-resident, no deadlock).
// ---------------------------------------------------------------------------
__global__ __launch_bounds__(256) void lstm_kernel(
    const float* __restrict__ xz,   // [B*T, 1024]
    const float* __restrict__ Wr,   // [256, 1024]
    const float* __restrict__ h0,   // may be null (zeros); stride h0_stride per batch
    int h0_stride,
    const float* __restrict__ c0,   // may be null (zeros); stride HID per batch
    float* __restrict__ Hout,       // [B*T, 256]
    float* __restrict__ c_fin,      // [B, 256] or null
    int* __restrict__ cnt,          // [B*T] zeroed flags
    int T)
{
  const int b = blockIdx.x & (BB - 1);
  const int s = blockIdx.x >> 4;
  const int tid = threadIdx.x;

  __shared__ float w[HID][CPS];       // 64 KB: Wr slice, w[j][c], c = gate*16+u
  __shared__ float hprev[HID];
  __shared__ float part[4][CPS + 4];
  __shared__ float zbuf[CPS];
  __shared__ float cstate[UPS];

  for (int i = tid; i < HID * CPS; i += 256) {
    int j = i >> 6, c = i & 63;
    int gam = c >> 4, u = c & 15;
    w[j][c] = Wr[(size_t)j * G4 + gam * HID + s * UPS + u];
  }
  if (tid < UPS) cstate[tid] = c0 ? c0[b * HID + s * UPS + tid] : 0.0f;
  if (tid < HID) hprev[tid] = h0 ? h0[(size_t)b * h0_stride + tid] : 0.0f;
  __syncthreads();

  const int c  = tid & 63;
  const int kq = tid >> 6;

  for (int t = 0; t < T; ++t) {
    // partial dot: z_part[c] = sum_{j in kq*64..+64} hprev[j] * w[j][c]
    float acc = 0.0f;
    const float4* h4p = (const float4*)(&hprev[kq * 64]);
#pragma unroll
    for (int jj = 0; jj < 16; ++jj) {
      float4 h4 = h4p[jj];
      int j = kq * 64 + jj * 4;
      acc = fmaf(h4.x, w[j + 0][c], acc);
      acc = fmaf(h4.y, w[j + 1][c], acc);
      acc = fmaf(h4.z, w[j + 2][c], acc);
      acc = fmaf(h4.w, w[j + 3][c], acc);
    }
    part[kq][c] = acc;
    __syncthreads();

    if (tid < CPS) {
      int gam = tid >> 4, u = tid & 15;
      float z = part[0][tid] + part[1][tid] + part[2][tid] + part[3][tid]
              + xz[(size_t)(b * T + t) * G4 + gam * HID + s * UPS + u];
      zbuf[tid] = z;
    }
    __syncthreads();

    if (tid < UPS) {
      float zi = zbuf[tid], zf = zbuf[16 + tid], zg = zbuf[32 + tid], zo = zbuf[48 + tid];
      float si = 1.0f / (1.0f + __expf(-zi));
      float sf = 1.0f / (1.0f + __expf(-zf));
      float so = 1.0f / (1.0f + __expf(-zo));
      float tg = tanhf(zg);
      float cn = fmaf(sf, cstate[tid], si * tg);
      cstate[tid] = cn;
      float hn = so * tanhf(cn);
      // agent-scope store -> visible at coherence point for other XCDs
      __hip_atomic_store(&Hout[(size_t)(b * T + t) * HID + s * UPS + tid], hn,
                         __ATOMIC_RELAXED, __HIP_MEMORY_SCOPE_AGENT);
    }
    __syncthreads();   // drains vmcnt: h stores complete before flag
    if (tid == 0)
      __hip_atomic_fetch_add(&cnt[b * T + t], 1, __ATOMIC_RELEASE, __HIP_MEMORY_SCOPE_AGENT);

    if (t + 1 < T) {
      if (tid == 0) {
        while (__hip_atomic_load(&cnt[b * T + t], __ATOMIC_ACQUIRE, __HIP_MEMORY_SCOPE_AGENT) < NSLICE)
          __builtin_amdgcn_s_sleep(1);
      }
      __syncthreads();
      // reload full h (256 threads, 1 elem each), coherent loads
      hprev[tid] = __hip_atomic_load(&Hout[(size_t)(b * T + t) * HID + tid],
                                     __ATOMIC_RELAXED, __HIP_MEMORY_SCOPE_AGENT);
      __syncthreads();
    }
  }
  if (c_fin && tid < UPS) c_fin[b * HID + s * UPS + tid] = cstate[tid];
}

// ---------------------------------------------------------------------------
// Kernel 3: attention + feat pack. block per (b,t), 256 threads.
// scores[s2] = dot(S_[b,t], Henc[b,s2]); softmax; A = p @ Henc.
// feat[m] = [S[m] (256) | A (256)]
// ---------------------------------------------------------------------------
__global__ __launch_bounds__(256) void attn_kernel(
    const float* __restrict__ Henc, const float* __restrict__ S,
    float* __restrict__ feat)
{
  const int m = blockIdx.x;          // b*LT + t
  const int b = m >> 7, t = m & (LT - 1);
  const int tid = threadIdx.x;

  __shared__ float srow[HID];
  __shared__ float p[LS];
  __shared__ float sm[LS];

  const float* s_ = (t == 0) ? (Henc + ((size_t)b * LS + (LS - 1)) * HID)
                             : (S + (size_t)(m - 1) * HID);
  srow[tid] = s_[tid];
  __syncthreads();

  const float4* h4 = (const float4*)(Henc + ((size_t)b * LS + tid) * HID);
  const float4* s4 = (const float4*)srow;
  float sc = 0.0f;
#pragma unroll 8
  for (int k = 0; k < HID / 4; ++k) {
    float4 a = h4[k], q = s4[k];
    sc += a.x * q.x + a.y * q.y + a.z * q.z + a.w * q.w;
  }
  sm[tid] = sc;
  __syncthreads();
  for (int st = 128; st > 0; st >>= 1) {
    if (tid < st) sm[tid] = fmaxf(sm[tid], sm[tid + st]);
    __syncthreads();
  }
  float mx = sm[0];
  __syncthreads();
  float e = __expf(sc - mx);
  p[tid] = e;
  sm[tid] = e;
  __syncthreads();
  for (int st = 128; st > 0; st >>= 1) {
    if (tid < st) sm[tid] += sm[tid + st];
    __syncthreads();
  }
  float inv = 1.0f / sm[0];

  float a_d = 0.0f;
#pragma unroll 4
  for (int s2 = 0; s2 < LS; ++s2)
    a_d = fmaf(p[s2], Henc[((size_t)b * LS + s2) * HID + tid], a_d);
  a_d *= inv;

  feat[(size_t)m * (2 * HID) + tid]       = S[(size_t)m * HID + tid];
  feat[(size_t)m * (2 * HID) + HID + tid] = a_d;
}

// ---------------------------------------------------------------------------
// Kernel 4: logits = feat @ Wout + bout  (fp32 vector GEMM, FMA-bound)
// bid = n_chunk*128 + m_chunk; thread owns one n, 16 m-rows (feat via s_loads).
// ---------------------------------------------------------------------------
__global__ __launch_bounds__(256) void proj_kernel(
    const float* __restrict__ feat, const float* __restrict__ Wout,
    const float* __restrict__ bout, float* __restrict__ logits)
{
  const int bid = blockIdx.x;
  const int n_chunk = bid >> 7;        // 0..124
  const int m_chunk = bid & 127;       // 0..127
  const int n  = n_chunk * 256 + threadIdx.x;
  const int m0 = m_chunk * 16;
  const float* f = feat + (size_t)m0 * 512;

  float acc[16];
#pragma unroll
  for (int i = 0; i < 16; ++i) acc[i] = 0.0f;

#pragma unroll 4
  for (int k = 0; k < 512; ++k) {
    float wv = Wout[(size_t)k * VOCAB + n];
#pragma unroll
    for (int i = 0; i < 16; ++i) acc[i] = fmaf(f[i * 512 + k], wv, acc[i]);
  }
  float bb = bout[n];
#pragma unroll
  for (int i = 0; i < 16; ++i)
    logits[(size_t)(m0 + i) * VOCAB + n] = acc[i] + bb;
}

// ---------------------------------------------------------------------------
// Kernel 5: in-place row softmax over VOCAB. block per row, 1024 threads,
// register-staged (32 vals/thread) -> single global read + single write.
// ---------------------------------------------------------------------------
__global__ __launch_bounds__(1024) void softmax_kernel(float* __restrict__ logits)
{
  const int m = blockIdx.x;
  float* row = logits + (size_t)m * VOCAB;
  const int tid = threadIdx.x;
  const int wid = tid >> 6, lane = tid & 63;
  __shared__ float red[16];

  float v[32];
  float mx = -1e30f;
#pragma unroll
  for (int q = 0; q < 32; ++q) {
    int i = q * 1024 + tid;
    v[q] = (i < VOCAB) ? row[i] : -1e30f;
    mx = fmaxf(mx, v[q]);
  }
  for (int off = 32; off > 0; off >>= 1) mx = fmaxf(mx, __shfl_down(mx, off, 64));
  if (lane == 0) red[wid] = mx;
  __syncthreads();
  if (tid == 0) {
    float r = red[0];
    for (int i = 1; i < 16; ++i) r = fmaxf(r, red[i]);
    red[0] = r;
  }
  __syncthreads();
  mx = red[0];
  __syncthreads();

  float ssum = 0.0f;
#pragma unroll
  for (int q = 0; q < 32; ++q) {
    v[q] = __expf(v[q] - mx);   // padded lanes: exp(-huge) = 0
    ssum += v[q];
  }
  for (int off = 32; off > 0; off >>= 1) ssum += __shfl_down(ssum, off, 64);
  if (lane == 0) red[wid] = ssum;
  __syncthreads();
  if (tid == 0) {
    float r = 0.0f;
    for (int i = 0; i < 16; ++i) r += red[i];
    red[0] = r;
  }
  __syncthreads();
  float inv = 1.0f / red[0];

#pragma unroll
  for (int q = 0; q < 32; ++q) {
    int i = q * 1024 + tid;
    if (i < VOCAB) row[i] = v[q] * inv;
  }
}

// ---------------------------------------------------------------------------
// Host launcher
// ---------------------------------------------------------------------------
extern "C" void kernel_launch(void* const* d_in, const int* in_sizes, int n_in,
                              void* d_out, int out_size, void* d_ws, size_t ws_size,
                              hipStream_t stream) {
  (void)in_sizes; (void)n_in; (void)out_size; (void)ws_size;

  const int*   x       = (const int*)d_in[0];
  const int*   y       = (const int*)d_in[1];
  const float* enc_emb = (const float*)d_in[2];
  const float* enc_Wk  = (const float*)d_in[3];
  const float* enc_Wr  = (const float*)d_in[4];
  const float* enc_b   = (const float*)d_in[5];
  const float* dec_emb = (const float*)d_in[6];
  const float* dec_Wk  = (const float*)d_in[7];
  const float* dec_Wr  = (const float*)d_in[8];
  const float* dec_b   = (const float*)d_in[9];
  const float* Wout    = (const float*)d_in[10];
  const float* bout    = (const float*)d_in[11];
  float* out = (float*)d_out;
  char*  ws  = (char*)d_ws;

  // workspace layout (bytes)
  size_t off = 0;
  float* xz_enc = (float*)(ws + off); off += (size_t)BB * LS * G4 * 4;   // 16 MB
  float* xz_dec = (float*)(ws + off); off += (size_t)BB * LT * G4 * 4;   //  8 MB
  float* Henc   = (float*)(ws + off); off += (size_t)BB * LS * HID * 4;  //  4 MB
  float* S      = (float*)(ws + off); off += (size_t)BB * LT * HID * 4;  //  2 MB
  float* feat   = (float*)(ws + off); off += (size_t)BB * LT * 2 * HID * 4; // 4 MB
  float* c_fin  = (float*)(ws + off); off += (size_t)BB * HID * 4;
  int*   cnt    = (int*)(ws + off);   off += (size_t)BB * (LS + LT) * 4;

  // zero the step flags (poisoned between replays)
  hipMemsetAsync(cnt, 0, (size_t)BB * (LS + LT) * 4, stream);

  // input projections
  embed_proj_kernel<<<(BB * LS) / 8, 256, 0, stream>>>(x, enc_emb, enc_Wk, enc_b, xz_enc);
  embed_proj_kernel<<<(BB * LT) / 8, 256, 0, stream>>>(y, dec_emb, dec_Wk, dec_b, xz_dec);

  // encoder LSTM (h0=c0=0)
  lstm_kernel<<<NSLICE * BB, 256, 0, stream>>>(
      xz_enc, enc_Wr, nullptr, 0, nullptr, Henc, c_fin, cnt, LS);

  // decoder LSTM (h0 = enc final h rows inside Henc, c0 = c_fin)
  lstm_kernel<<<NSLICE * BB, 256, 0, stream>>>(
      xz_dec, dec_Wr, Henc + (size_t)(LS - 1) * HID, LS * HID, c_fin,
      S, nullptr, cnt + BB * LS, LT);

  // attention + feat pack
  attn_kernel<<<BB * LT, 256, 0, stream>>>(Henc, S, feat);

  // vocab projection (logits into d_out)
  proj_kernel<<<125 * 128, 256, 0, stream>>>(feat, Wout, bout, out);

  // in-place softmax
  softmax_kernel<<<BB * LT, 1024, 0, stream>>>(out);
}

// Round 2
// 1670.131 us; speedup vs baseline: 2.3598x; 2.3598x over previous
//
#include <hip/hip_runtime.h>
#include <hip/hip_bf16.h>
#include <math.h>

// Problem constants
#define BB    16
#define LS    256
#define LT    128
#define EMB   128
#define HID   256
#define G4    1024      // 4*HID
#define VOCAB 32000

// LSTM slicing: 8 slice-WGs per batch, each owns 32 hidden units (128 gate cols)
#define NSL   8
#define UPSL  32        // units per slice
#define CPSL  128       // gate cols per slice

typedef __attribute__((ext_vector_type(8))) short bf16x8;
typedef __attribute__((ext_vector_type(4))) float f32x4;
typedef unsigned short ushort_t;

// ---------------------------------------------------------------------------
// Kernel 1: xz = emb[idx] @ Wk + b   (input projection, precomputed per t)
// ---------------------------------------------------------------------------
__global__ __launch_bounds__(256) void embed_proj_kernel(
    const int* __restrict__ idx, const float* __restrict__ emb,
    const float* __restrict__ Wk, const float* __restrict__ bias,
    float* __restrict__ xz)
{
  __shared__ float e[8][EMB];
  const int row0 = blockIdx.x * 8;
  const int tid = threadIdx.x;

  for (int i = tid; i < 8 * EMB; i += 256) {
    int r = i >> 7, k = i & 127;
    int token = idx[row0 + r];
    e[r][k] = emb[(size_t)token * EMB + k];
  }
  __syncthreads();

  float acc[4][8];
#pragma unroll
  for (int q = 0; q < 4; ++q)
#pragma unroll
    for (int r = 0; r < 8; ++r) acc[q][r] = 0.0f;

  for (int k = 0; k < EMB; ++k) {
    float w0 = Wk[(size_t)k * G4 + 0 * 256 + tid];
    float w1 = Wk[(size_t)k * G4 + 1 * 256 + tid];
    float w2 = Wk[(size_t)k * G4 + 2 * 256 + tid];
    float w3 = Wk[(size_t)k * G4 + 3 * 256 + tid];
#pragma unroll
    for (int r = 0; r < 8; ++r) {
      float ev = e[r][k];
      acc[0][r] = fmaf(ev, w0, acc[0][r]);
      acc[1][r] = fmaf(ev, w1, acc[1][r]);
      acc[2][r] = fmaf(ev, w2, acc[2][r]);
      acc[3][r] = fmaf(ev, w3, acc[3][r]);
    }
  }
#pragma unroll
  for (int q = 0; q < 4; ++q) {
    float bb = bias[q * 256 + tid];
#pragma unroll
    for (int r = 0; r < 8; ++r)
      xz[(size_t)(row0 + r) * G4 + q * 256 + tid] = acc[q][r] + bb;
  }
}

// ---------------------------------------------------------------------------
// Kernel 2: LSTM recurrence, 8 slice-WGs per batch (128 WGs, 1 WG/CU).
// Weights in VGPRs (128/thread). h broadcast via v_readlane.
// Cross-WG sync: RELAXED agent stores/loads only; per-slice step-stamped
// flag (own 64B line); ordering via explicit s_waitcnt vmcnt(0).
// ---------------------------------------------------------------------------
__global__ __launch_bounds__(256, 1) void lstm_kernel(
    const float* __restrict__ xz,   // [B*T, 1024]
    const float* __restrict__ Wr,   // [256, 1024]
    const float* __restrict__ h0,   // may be null (zeros); stride h0_stride per batch
    int h0_stride,
    const float* __restrict__ c0,   // may be null (zeros); [B,256]
    float* __restrict__ Hout,       // [B*T, 256]
    float* __restrict__ c_fin,      // [B, 256] or null
    int* __restrict__ flags,        // [B*NSL*16] zeroed step stamps
    int T)
{
  const int b    = blockIdx.x & (BB - 1);
  const int s    = blockIdx.x >> 4;
  const int tid  = threadIdx.x;
  const int col  = tid & (CPSL - 1);   // 0..127 : gate = col>>5, u = col&31
  const int half = tid >> 7;           // 0: j 0..127, 1: j 128..255
  const int lane = tid & 63;
  const int gate = col >> 5, u = col & 31;

  __shared__ float part[2][CPSL];

  // ---- load this thread's weight column slice into registers ----
  // w_r[j] = Wr[half*128 + j][gate*256 + s*32 + u]
  float w_r[128];
  {
    const float* wp = Wr + (size_t)(half * 128) * G4 + gate * 256 + s * UPSL + u;
#pragma unroll
    for (int j = 0; j < 128; ++j) w_r[j] = wp[(size_t)j * G4];
  }

  // ---- initial h (in regs, per-wave half) and c (threads 0..31) ----
  float hv0, hv1;
  if (h0) {
    hv0 = h0[(size_t)b * h0_stride + half * 128 + lane];
    hv1 = h0[(size_t)b * h0_stride + half * 128 + 64 + lane];
  } else { hv0 = 0.0f; hv1 = 0.0f; }
  float cst = 0.0f;
  if (tid < UPSL) cst = c0 ? c0[b * HID + s * UPSL + tid] : 0.0f;

  int* myflags = flags + b * NSL * 16;

  for (int t = 0; t < T; ++t) {
    // prefetch xz gate values for the pointwise phase (threads 0..31)
    float xzv0 = 0.f, xzv1 = 0.f, xzv2 = 0.f, xzv3 = 0.f;
    if (tid < UPSL) {
      const float* xp = xz + (size_t)(b * T + t) * G4 + s * UPSL + tid;
      xzv0 = xp[0]; xzv1 = xp[256]; xzv2 = xp[512]; xzv3 = xp[768];
    }

    // ---- partial dot: acc = sum_j h[half*128+j] * w_r[j] ----
    float acc = 0.0f;
#pragma unroll
    for (int j = 0; j < 64; ++j) {
      float sa = __int_as_float(__builtin_amdgcn_readlane(__float_as_int(hv0), j));
      acc = fmaf(sa, w_r[j], acc);
    }
#pragma unroll
    for (int j = 0; j < 64; ++j) {
      float sb = __int_as_float(__builtin_amdgcn_readlane(__float_as_int(hv1), j));
      acc = fmaf(sb, w_r[64 + j], acc);
    }
    part[half][col] = acc;
    __syncthreads();

    // ---- pointwise gates (threads 0..31 = units of this slice) ----
    if (tid < UPSL) {
      float zi = part[0][0 * UPSL + u] + part[1][0 * UPSL + u] + xzv0;
      float zf = part[0][1 * UPSL + u] + part[1][1 * UPSL + u] + xzv1;
      float zg = part[0][2 * UPSL + u] + part[1][2 * UPSL + u] + xzv2;
      float zo = part[0][3 * UPSL + u] + part[1][3 * UPSL + u] + xzv3;
      float si = 1.0f / (1.0f + __expf(-zi));
      float sf = 1.0f / (1.0f + __expf(-zf));
      float so = 1.0f / (1.0f + __expf(-zo));
      float tg = tanhf(zg);
      cst = fmaf(sf, cst, si * tg);
      float hn = so * tanhf(cst);
      __hip_atomic_store(&Hout[((size_t)b * T + t) * HID + s * UPSL + tid], hn,
                         __ATOMIC_RELAXED, __HIP_MEMORY_SCOPE_AGENT);
    }
    // wave 0: drain h stores to the coherence point, then stamp flag
    if (tid < 64) {
      asm volatile("s_waitcnt vmcnt(0)" ::: "memory");
      if (tid == 0)
        __hip_atomic_store(&myflags[s * 16], t + 1,
                           __ATOMIC_RELAXED, __HIP_MEMORY_SCOPE_AGENT);
    }

    // ---- wait for all 8 slices, then reload h halves into regs ----
    if (t + 1 < T) {
      const float* hrow = Hout + ((size_t)b * T + t) * HID;
      const int need = t + 1;
      for (;;) {
        int fj = need;
        if (lane < NSL)
          fj = __hip_atomic_load(&myflags[lane * 16],
                                 __ATOMIC_RELAXED, __HIP_MEMORY_SCOPE_AGENT);
        if (__all(fj >= need)) break;
      }
      asm volatile("" ::: "memory");
      hv0 = __hip_atomic_load(&hrow[half * 128 + lane],
                              __ATOMIC_RELAXED, __HIP_MEMORY_SCOPE_AGENT);
      hv1 = __hip_atomic_load(&hrow[half * 128 + 64 + lane],
                              __ATOMIC_RELAXED, __HIP_MEMORY_SCOPE_AGENT);
    }
  }
  if (c_fin && tid < UPSL) c_fin[b * HID + s * UPSL + tid] = cst;
}

// ---------------------------------------------------------------------------
// Kernel 3: attention + feat pack -> featB (bf16 [M=2048][K=512]).
// ---------------------------------------------------------------------------
__global__ __launch_bounds__(256) void attn_kernel(
    const float* __restrict__ Henc, const float* __restrict__ S,
    __hip_bfloat16* __restrict__ featB)
{
  const int m = blockIdx.x;          // b*LT + t
  const int b = m >> 7, t = m & (LT - 1);
  const int tid = threadIdx.x;

  __shared__ float srow[HID];
  __shared__ float p[LS];
  __shared__ float sm[LS];

  const float* s_ = (t == 0) ? (Henc + ((size_t)b * LS + (LS - 1)) * HID)
                             : (S + (size_t)(m - 1) * HID);
  srow[tid] = s_[tid];
  __syncthreads();

  const float4* h4 = (const float4*)(Henc + ((size_t)b * LS + tid) * HID);
  const float4* s4 = (const float4*)srow;
  float sc = 0.0f;
#pragma unroll 8
  for (int k = 0; k < HID / 4; ++k) {
    float4 a = h4[k], q = s4[k];
    sc += a.x * q.x + a.y * q.y + a.z * q.z + a.w * q.w;
  }
  sm[tid] = sc;
  __syncthreads();
  for (int st = 128; st > 0; st >>= 1) {
    if (tid < st) sm[tid] = fmaxf(sm[tid], sm[tid + st]);
    __syncthreads();
  }
  float mx = sm[0];
  __syncthreads();
  float e = __expf(sc - mx);
  p[tid] = e;
  sm[tid] = e;
  __syncthreads();
  for (int st = 128; st > 0; st >>= 1) {
    if (tid < st) sm[tid] += sm[tid + st];
    __syncthreads();
  }
  float inv = 1.0f / sm[0];

  float a_d = 0.0f;
#pragma unroll 4
  for (int s2 = 0; s2 < LS; ++s2)
    a_d = fmaf(p[s2], Henc[((size_t)b * LS + s2) * HID + tid], a_d);
  a_d *= inv;

  featB[(size_t)m * (2 * HID) + tid]       = __float2bfloat16(S[(size_t)m * HID + tid]);
  featB[(size_t)m * (2 * HID) + HID + tid] = __float2bfloat16(a_d);
}

// ---------------------------------------------------------------------------
// Kernel 4: logits = featB @ Wout + bout via bf16 MFMA 16x16x32.
// No LDS: A fragments 16B-vector loads from featB [M][K]; B fragments
// gathered from fp32 Wout [K][N] with on-the-fly bf16 pack (L2-resident).
// Tile 128x128/WG, 4 waves in 2x2, each wave 64x64 (4x4 fragments).
// ---------------------------------------------------------------------------
__global__ __launch_bounds__(256) void proj_mfma_kernel(
    const ushort_t* __restrict__ A,     // featB bf16 [2048][512]
    const float* __restrict__ Wout,     // [512][32000] fp32
    const float* __restrict__ bout,
    float* __restrict__ out)            // [2048][32000] fp32 logits
{
  const int mt = blockIdx.x / 250;
  const int nt = blockIdx.x % 250;
  const int wave = threadIdx.x >> 6;
  const int lane = threadIdx.x & 63;
  const int wm = wave >> 1, wn = wave & 1;
  const int r  = lane & 15, kg = lane >> 4;

  const int m0 = mt * 128 + wm * 64;
  const int n0 = nt * 128 + wn * 64;

  f32x4 acc[4][4];
#pragma unroll
  for (int i = 0; i < 4; ++i)
#pragma unroll
    for (int j = 0; j < 4; ++j) acc[i][j] = (f32x4){0.f, 0.f, 0.f, 0.f};

  for (int ks = 0; ks < 16; ++ks) {
    const int kb = ks * 32 + kg * 8;
    bf16x8 a[4], bb[4];
#pragma unroll
    for (int i = 0; i < 4; ++i)
      a[i] = *(const bf16x8*)(A + (size_t)(m0 + i * 16 + r) * 512 + kb);
#pragma unroll
    for (int j = 0; j < 4; ++j) {
      const float* wp = Wout + (size_t)kb * VOCAB + (n0 + j * 16 + r);
      bf16x8 bv;
#pragma unroll
      for (int e2 = 0; e2 < 8; ++e2) {
        unsigned bw = __float_as_uint(wp[(size_t)e2 * VOCAB]);
        bv[e2] = (short)(ushort_t)((bw + 0x8000u) >> 16);   // round-half-up to bf16
      }
      bb[j] = bv;
    }
#pragma unroll
    for (int i = 0; i < 4; ++i)
#pragma unroll
      for (int j = 0; j < 4; ++j)
        acc[i][j] = __builtin_amdgcn_mfma_f32_16x16x32_bf16(a[i], bb[j], acc[i][j], 0, 0, 0);
  }

  float bv4[4];
#pragma unroll
  for (int j = 0; j < 4; ++j) bv4[j] = bout[n0 + j * 16 + r];

#pragma unroll
  for (int i = 0; i < 4; ++i)
#pragma unroll
    for (int j = 0; j < 4; ++j)
#pragma unroll
      for (int q = 0; q < 4; ++q) {
        int row = m0 + i * 16 + kg * 4 + q;
        int cix = n0 + j * 16 + r;
        out[(size_t)row * VOCAB + cix] = acc[i][j][q] + bv4[j];
      }
}

// ---------------------------------------------------------------------------
// Kernel 5: in-place row softmax over VOCAB (register-staged single pass).
// ---------------------------------------------------------------------------
__global__ __launch_bounds__(1024) void softmax_kernel(float* __restrict__ logits)
{
  const int m = blockIdx.x;
  float* row = logits + (size_t)m * VOCAB;
  const int tid = threadIdx.x;
  const int wid = tid >> 6, lane = tid & 63;
  __shared__ float red[16];

  float v[32];
  float mx = -1e30f;
#pragma unroll
  for (int q = 0; q < 32; ++q) {
    int i = q * 1024 + tid;
    v[q] = (i < VOCAB) ? row[i] : -1e30f;
    mx = fmaxf(mx, v[q]);
  }
  for (int off = 32; off > 0; off >>= 1) mx = fmaxf(mx, __shfl_down(mx, off, 64));
  if (lane == 0) red[wid] = mx;
  __syncthreads();
  if (tid == 0) {
    float r = red[0];
    for (int i = 1; i < 16; ++i) r = fmaxf(r, red[i]);
    red[0] = r;
  }
  __syncthreads();
  mx = red[0];
  __syncthreads();

  float ssum = 0.0f;
#pragma unroll
  for (int q = 0; q < 32; ++q) {
    v[q] = __expf(v[q] - mx);
    ssum += v[q];
  }
  for (int off = 32; off > 0; off >>= 1) ssum += __shfl_down(ssum, off, 64);
  if (lane == 0) red[wid] = ssum;
  __syncthreads();
  if (tid == 0) {
    float r = 0.0f;
    for (int i = 0; i < 16; ++i) r += red[i];
    red[0] = r;
  }
  __syncthreads();
  float inv = 1.0f / red[0];

#pragma unroll
  for (int q = 0; q < 32; ++q) {
    int i = q * 1024 + tid;
    if (i < VOCAB) row[i] = v[q] * inv;
  }
}

// ---------------------------------------------------------------------------
// Host launcher
// ---------------------------------------------------------------------------
extern "C" void kernel_launch(void* const* d_in, const int* in_sizes, int n_in,
                              void* d_out, int out_size, void* d_ws, size_t ws_size,
                              hipStream_t stream) {
  (void)in_sizes; (void)n_in; (void)out_size; (void)ws_size;

  const int*   x       = (const int*)d_in[0];
  const int*   y       = (const int*)d_in[1];
  const float* enc_emb = (const float*)d_in[2];
  const float* enc_Wk  = (const float*)d_in[3];
  const float* enc_Wr  = (const float*)d_in[4];
  const float* enc_b   = (const float*)d_in[5];
  const float* dec_emb = (const float*)d_in[6];
  const float* dec_Wk  = (const float*)d_in[7];
  const float* dec_Wr  = (const float*)d_in[8];
  const float* dec_b   = (const float*)d_in[9];
  const float* Wout    = (const float*)d_in[10];
  const float* bout    = (const float*)d_in[11];
  float* out = (float*)d_out;
  char*  ws  = (char*)d_ws;

  // workspace layout (bytes)
  size_t off = 0;
  float* xz_enc = (float*)(ws + off); off += (size_t)BB * LS * G4 * 4;      // 16 MB
  float* xz_dec = (float*)(ws + off); off += (size_t)BB * LT * G4 * 4;      //  8 MB
  float* Henc   = (float*)(ws + off); off += (size_t)BB * LS * HID * 4;     //  4 MB
  float* S      = (float*)(ws + off); off += (size_t)BB * LT * HID * 4;     //  2 MB
  __hip_bfloat16* featB = (__hip_bfloat16*)(ws + off);
  off += (size_t)BB * LT * 2 * HID * 2;                                     //  2 MB
  float* c_fin  = (float*)(ws + off); off += (size_t)BB * HID * 4;
  int*   flags  = (int*)(ws + off);   off += (size_t)2 * BB * NSL * 16 * 4; // enc+dec

  // zero the step flags (fresh stamps each launch/replay)
  hipMemsetAsync(flags, 0, (size_t)2 * BB * NSL * 16 * 4, stream);

  // input projections
  embed_proj_kernel<<<(BB * LS) / 8, 256, 0, stream>>>(x, enc_emb, enc_Wk, enc_b, xz_enc);
  embed_proj_kernel<<<(BB * LT) / 8, 256, 0, stream>>>(y, dec_emb, dec_Wk, dec_b, xz_dec);

  // encoder LSTM (h0=c0=0): 128 WGs, 1/CU
  lstm_kernel<<<NSL * BB, 256, 0, stream>>>(
      xz_enc, enc_Wr, nullptr, 0, nullptr, Henc, c_fin, flags, LS);

  // decoder LSTM (h0 = enc final h rows inside Henc, c0 = c_fin)
  lstm_kernel<<<NSL * BB, 256, 0, stream>>>(
      xz_dec, dec_Wr, Henc + (size_t)(LS - 1) * HID, LS * HID, c_fin,
      S, nullptr, flags + BB * NSL * 16, LT);

  // attention + bf16 feat pack
  attn_kernel<<<BB * LT, 256, 0, stream>>>(Henc, S, featB);

  // vocab projection via MFMA (logits into d_out)
  proj_mfma_kernel<<<16 * 250, 256, 0, stream>>>(
      (const ushort_t*)featB, Wout, bout, out);

  // in-place softmax
  softmax_kernel<<<BB * LT, 1024, 0, stream>>>(out);
}